// Round 3
// baseline (2170.496 us; speedup 1.0000x reference)
//
#include <hip/hip_runtime.h>
#include <hip/hip_bf16.h>
#include <math.h>

typedef unsigned short u16;
typedef __attribute__((ext_vector_type(8))) short short8;
typedef __attribute__((ext_vector_type(4))) float f32x4;

#define T_STEPS 10
#define NB 8
#define HH 64
#define WW 64
#define FF 64
#define NGATE 256
#define HP 66
#define PIX (NB*HH*WW)          // 32768

__device__ __forceinline__ u16 f2bf(float f) {
    unsigned u = __float_as_uint(f);
    u += 0x7FFF + ((u >> 16) & 1);   // round-to-nearest-even
    return (u16)(u >> 16);
}
__device__ __forceinline__ float hsig(float x) {
    return fminf(fmaxf(0.2f * x + 0.5f, 0.0f), 1.0f);
}
__device__ __forceinline__ float ftanh(float x) {
    float e = __expf(2.0f * x);
    return 1.0f - 2.0f / (e + 1.0f);
}
// LDS-only barrier: does NOT drain vmcnt, so register-prefetch global loads
// issued before it stay in flight through the MFMA phase. (__syncthreads()
// emits s_waitcnt vmcnt(0) before s_barrier, defeating prefetch.)
__device__ __forceinline__ void lds_barrier() {
    asm volatile("s_waitcnt lgkmcnt(0)\n\ts_barrier" ::: "memory");
}

// Transpose fp32 [K][256] weight(s) -> bf16 BT [256][K].
__global__ void wtrans_kernel(const float* __restrict__ W0,
                              const float* __restrict__ W1,
                              u16* __restrict__ BT, int K) {
    int total = K * NGATE;
    for (int o = blockIdx.x * blockDim.x + threadIdx.x; o < total;
         o += gridDim.x * blockDim.x) {
        int n = o / K, k = o - n * K;
        float v = (k < 576) ? W0[k * NGATE + n] : W1[(k - 576) * NGATE + n];
        BT[o] = f2bf(v);
    }
}

// Fused dual-layer ConvLSTM tick. Even blocks: layer-0 step u; odd blocks:
// layer-1 step u-1 (both only READ h0_prev -> no intra-launch dependency).
// Per role-block: implicit-GEMM 64px x 256 gates, 4 waves, per-wave 4x4
// 16x16x32 MFMA fragments, register-prefetched staging.
__global__ __launch_bounds__(256, 3)
void fused_step_kernel(const u16* __restrict__ h0_prev, u16* __restrict__ h0_new,
                       const u16* __restrict__ h1_prev, u16* __restrict__ h1_new,
                       const u16* __restrict__ B0T, const u16* __restrict__ B1T,
                       const float* __restrict__ x, const float* __restrict__ k0w,
                       const float* __restrict__ b0, const float* __restrict__ b1,
                       float* __restrict__ c0, float* __restrict__ c1,
                       float* __restrict__ oh0, float* __restrict__ oc0,
                       float* __restrict__ oh1, float* __restrict__ oc1,
                       int u) {
    int blk = blockIdx.x;
    int role = blk & 1;              // 0: layer-0 step u; 1: layer-1 step u-1
    int pxb = blk >> 1;              // 512 pixel-blocks per role
    if (role == 0 && u >= T_STEPS) return;
    if (role == 1 && u == 0) return;

    __shared__ __align__(16) u16 sA[64][72];
    __shared__ __align__(16) u16 sB[256][72];
    __shared__ float xs[3][WW + 2];

    int tid = threadIdx.x;
    int b = pxb >> 6, y = pxb & 63;  // batch, image row
    const u16* BT = role ? B1T : B0T;
    int K = role ? 1152 : 576;
    int nch = K >> 6;

    // Layer-0: stage x halo rows for the fused Cin=1 input conv (epilogue).
    if (role == 0 && tid < 3 * (WW + 2)) {
        int dyi = tid / (WW + 2), xx = tid - dyi * (WW + 2);
        int yy = y + dyi - 1, col = xx - 1;
        float v = 0.0f;
        if (yy >= 0 && yy < HH && col >= 0 && col < WW)
            v = x[(((size_t)b * T_STEPS + u) * HH + yy) * WW + col];
        xs[dyi][xx] = v;
    }

    int a_px = tid >> 2, a_q = tid & 3;   // A staging: pixel, 16-ch quarter

    uint4 ra0, ra1, rb[8];
    // ---- prefetch chunk 0 into registers ----
    {
        const u16* gp = h0_prev + (((size_t)(b * HP + y)) * HP + a_px) * FF + a_q * 16;
        ra0 = *(const uint4*)gp; ra1 = *(const uint4*)(gp + 8);
        const u16* gb = BT + (size_t)tid * K;
#pragma unroll
        for (int j = 0; j < 8; ++j) rb[j] = *(const uint4*)(gb + j * 8);
    }

    f32x4 acc[4][4];
#pragma unroll
    for (int mt = 0; mt < 4; ++mt)
#pragma unroll
        for (int g = 0; g < 4; ++g)
            acc[mt][g] = (f32x4){0.f, 0.f, 0.f, 0.f};

    int fq = tid >> 6, lane = tid & 63;
    int l15 = lane & 15, quad = lane >> 4;

    for (int kc = 0; kc < nch; ++kc) {
        lds_barrier();                    // previous chunk's ds_reads retired
        // stage chunk kc from registers (compiler inserts the vmcnt wait here)
        *(uint4*)&sA[a_px][a_q * 16]     = ra0;
        *(uint4*)&sA[a_px][a_q * 16 + 8] = ra1;
#pragma unroll
        for (int j = 0; j < 8; ++j) *(uint4*)&sB[tid][j * 8] = rb[j];
        // prefetch chunk kc+1 (in flight across the barrier + MFMA phase)
        if (kc + 1 < nch) {
            int kn = kc + 1;
            int tau = (kn < 9) ? kn : kn - 9;
            const u16* src = (kn < 9) ? h0_prev : h1_prev;
            int dy = tau / 3 - 1, dx = tau % 3 - 1;
            const u16* gp = src + (((size_t)(b * HP + y + dy + 1)) * HP +
                                   (a_px + dx + 1)) * FF + a_q * 16;
            ra0 = *(const uint4*)gp; ra1 = *(const uint4*)(gp + 8);
            const u16* gb = BT + (size_t)tid * K + kn * 64;
#pragma unroll
            for (int j = 0; j < 8; ++j) rb[j] = *(const uint4*)(gb + j * 8);
        }
        lds_barrier();                    // staged tile visible
#pragma unroll
        for (int ks = 0; ks < 2; ++ks) {
            short8 aF[4], bF[4];
            int ko = ks * 32 + quad * 8;
#pragma unroll
            for (int mt = 0; mt < 4; ++mt)
                aF[mt] = *(const short8*)&sA[mt * 16 + l15][ko];
#pragma unroll
            for (int g = 0; g < 4; ++g)
                bF[g] = *(const short8*)&sB[g * 64 + fq * 16 + l15][ko];
#pragma unroll
            for (int mt = 0; mt < 4; ++mt)
#pragma unroll
                for (int g = 0; g < 4; ++g)
                    acc[mt][g] = __builtin_amdgcn_mfma_f32_16x16x32_bf16(
                        aF[mt], bF[g], acc[mt][g], 0, 0, 0);
        }
    }

    // ---- epilogue: LSTM gate update (lane-local: f = fq*16+l15, 4 gates) ----
    const float* bias = role ? b1 : b0;
    float* cbuf = role ? c1 : c0;
    u16* hout = role ? h1_new : h0_new;
    int wo = role ? (u == T_STEPS) : (u == T_STEPS - 1);
    float* outh = role ? oh1 : oh0;
    float* outc = role ? oc1 : oc0;

    int f = fq * 16 + l15;
    float bi = bias[f], bff = bias[64 + f], bg = bias[128 + f], bo = bias[192 + f];
    float wk[4][9];
    if (role == 0) {
#pragma unroll
        for (int g = 0; g < 4; ++g)
#pragma unroll
            for (int tau = 0; tau < 9; ++tau)
                wk[g][tau] = k0w[tau * NGATE + g * 64 + f];
    }
#pragma unroll
    for (int mt = 0; mt < 4; ++mt) {
#pragma unroll
        for (int r = 0; r < 4; ++r) {
            int xcol = mt * 16 + quad * 4 + r;      // pixel x within the row
            size_t p = (size_t)pxb * 64 + xcol;     // global pixel
            float zi = acc[mt][0][r] + bi;
            float zf = acc[mt][1][r] + bff;
            float zg = acc[mt][2][r] + bg;
            float zo = acc[mt][3][r] + bo;
            if (role == 0) {   // fused layer-0 input conv, fp32 exact
#pragma unroll
                for (int tau = 0; tau < 9; ++tau) {
                    float xv = xs[tau / 3][xcol + tau % 3];
                    zi += xv * wk[0][tau];
                    zf += xv * wk[1][tau];
                    zg += xv * wk[2][tau];
                    zo += xv * wk[3][tau];
                }
            }
            float cold = cbuf[p * FF + f];
            float cn = hsig(zf) * cold + hsig(zi) * ftanh(zg);
            float hn = hsig(zo) * ftanh(cn);
            cbuf[p * FF + f] = cn;
            hout[(((size_t)(b * HP + y + 1)) * HP + (xcol + 1)) * FF + f] = f2bf(hn);
            if (wo) { outh[p * FF + f] = hn; outc[p * FF + f] = cn; }
        }
    }
}

extern "C" void kernel_launch(void* const* d_in, const int* in_sizes, int n_in,
                              void* d_out, int out_size, void* d_ws, size_t ws_size,
                              hipStream_t stream) {
    const float* x   = (const float*)d_in[0];
    const float* k0  = (const float*)d_in[1];
    const float* rk0 = (const float*)d_in[2];
    const float* b0  = (const float*)d_in[3];
    const float* k1  = (const float*)d_in[4];
    const float* rk1 = (const float*)d_in[5];
    const float* b1  = (const float*)d_in[6];
    float* out = (float*)d_out;

    char* ws = (char*)d_ws;
    const size_t HPAD_BYTES = (size_t)NB * HP * HP * FF * 2;  // 4,460,544
    const size_t C_BYTES    = (size_t)PIX * FF * 4;           // 8,388,608

    u16* h0p[2]; u16* h1p[2];
    h0p[0] = (u16*)(ws);
    h0p[1] = (u16*)(ws + HPAD_BYTES);
    h1p[0] = (u16*)(ws + 2 * HPAD_BYTES);
    h1p[1] = (u16*)(ws + 3 * HPAD_BYTES);
    float* c0 = (float*)(ws + 4 * HPAD_BYTES);
    float* c1 = (float*)(ws + 4 * HPAD_BYTES + C_BYTES);
    u16* B0T  = (u16*)(ws + 4 * HPAD_BYTES + 2 * C_BYTES);
    u16* B1T  = (u16*)(ws + 4 * HPAD_BYTES + 2 * C_BYTES + (size_t)576 * 256 * 2);

    // Zero h (incl. halo == SAME padding) and c states; ws is poisoned 0xAA.
    hipMemsetAsync(ws, 0, 4 * HPAD_BYTES + 2 * C_BYTES, stream);

    wtrans_kernel<<<256, 256, 0, stream>>>(rk0, rk0, B0T, 576);
    wtrans_kernel<<<256, 256, 0, stream>>>(k1, rk1, B1T, 1152);

    float* oh0 = out;
    float* oc0 = out + (size_t)PIX * FF;
    float* oh1 = out + 2 * (size_t)PIX * FF;
    float* oc1 = out + 3 * (size_t)PIX * FF;

    // Tick u: layer-0 computes step u (reads h0[u-1] -> writes h0[u]);
    //         layer-1 computes step u-1 (reads h0[u-1], h1[u-2] -> h1[u-1]).
    for (int u = 0; u <= T_STEPS; ++u) {
        const u16* h0_prev = h0p[(u + 1) & 1];
        u16*       h0_new  = h0p[u & 1];
        const u16* h1_prev = h1p[u & 1];
        u16*       h1_new  = h1p[(u + 1) & 1];
        fused_step_kernel<<<1024, 256, 0, stream>>>(
            h0_prev, h0_new, h1_prev, h1_new, B0T, B1T,
            x, k0, b0, b1, c0, c1, oh0, oc0, oh1, oc1, u);
    }
}

// Round 4
// 534.485 us; speedup vs baseline: 4.0609x; 4.0609x over previous
//
#include <hip/hip_runtime.h>
#include <hip/hip_bf16.h>

typedef unsigned short u16;
typedef __attribute__((ext_vector_type(8))) short short8;
typedef __attribute__((ext_vector_type(4))) float f32x4;

#define T_STEPS 10
#define NB 8
#define HH 64
#define WW 64
#define FF 64
#define NGATE 256
#define HP 66
#define PIX (NB*HH*WW)          // 32768

__device__ __forceinline__ u16 f2bf(float f) {
    unsigned u = __float_as_uint(f);
    u += 0x7FFF + ((u >> 16) & 1);   // round-to-nearest-even
    return (u16)(u >> 16);
}
__device__ __forceinline__ float hsig(float x) {
    return fminf(fmaxf(0.2f * x + 0.5f, 0.0f), 1.0f);
}
__device__ __forceinline__ float ftanh(float x) {
    float e = __expf(2.0f * x);
    return 1.0f - 2.0f / (e + 1.0f);
}
__device__ __forceinline__ void gll16(const void* g, void* l) {
    __builtin_amdgcn_global_load_lds(
        (const __attribute__((address_space(1))) unsigned*)g,
        (__attribute__((address_space(3))) unsigned*)l, 16, 0, 0);
}

// Build B in MFMA-fragment-stream order, bf16:
//   stream[kc][fq][ks][g][lane][e], lane=quad*16+l15, e=0..7
//   value = W[k = kc*64 + ks*32 + quad*8 + e][n = g*64 + fq*16 + l15]
// For K=1152 the first 576 k come from W0 (input kernel), rest from W1.
__global__ void wtrans_kernel(const float* __restrict__ W0,
                              const float* __restrict__ W1,
                              u16* __restrict__ BS, int K) {
    int total = (K >> 6) << 14;
    for (int o = blockIdx.x * blockDim.x + threadIdx.x; o < total;
         o += gridDim.x * blockDim.x) {
        int e = o & 7, lane = (o >> 3) & 63, g = (o >> 9) & 3;
        int ks = (o >> 11) & 1, fq = (o >> 12) & 3, kc = o >> 14;
        int quad = lane >> 4, l15 = lane & 15;
        int n = g * 64 + fq * 16 + l15;
        int k = kc * 64 + ks * 32 + quad * 8 + e;
        float v = (k < 576) ? W0[k * NGATE + n] : W1[(k - 576) * NGATE + n];
        BS[o] = f2bf(v);
    }
}

// Fused dual-layer ConvLSTM tick. Even blocks: layer-0 step u; odd blocks:
// layer-1 step u-1 (both only READ h0_prev -> independent).
// 64px x 256n tile, 4 waves (wave fq: n-cols fq*16+l15 in all 4 gate tiles).
// A: LDS double-buffer via global_load_lds, XOR-swizzled 16B chunks.
// B: direct from global fragment stream (zero LDS, coalesced lane*16).
__global__ __launch_bounds__(256, 4)
void fused_step_kernel(const u16* __restrict__ h0_prev, u16* __restrict__ h0_new,
                       const u16* __restrict__ h1_prev, u16* __restrict__ h1_new,
                       const u16* __restrict__ B0S, const u16* __restrict__ B1S,
                       const float* __restrict__ x, const float* __restrict__ k0w,
                       const float* __restrict__ b0, const float* __restrict__ b1,
                       float* __restrict__ c0, float* __restrict__ c1,
                       float* __restrict__ oh0, float* __restrict__ oc0,
                       float* __restrict__ oh1, float* __restrict__ oc1,
                       int u) {
    int blk = blockIdx.x;
    int role = blk & 1;              // 0: layer-0 step u; 1: layer-1 step u-1
    int pxb = blk >> 1;              // 512 pixel-blocks per role
    if (role == 0 && u >= T_STEPS) return;
    if (role == 1 && u == 0) return;

    // A tile: 512 16B-chunks; chunk q holds px=q>>3, ch-block (q&7)^(px&7).
    __shared__ __align__(16) u16 sA2[2][4096];
    __shared__ float xs[3][WW + 2];

    int tid = threadIdx.x;
    int lane = tid & 63, fq = tid >> 6;
    int quad = lane >> 4, l15 = lane & 15;
    int b = pxb >> 6, y = pxb & 63;  // batch, image row

    const u16* BS = role ? B1S : B0S;
    int nch = role ? 18 : 9;

    if (role == 0 && tid < 3 * (WW + 2)) {
        int dyi = tid / (WW + 2), xx = tid - dyi * (WW + 2);
        int yy = y + dyi - 1, col = xx - 1;
        float v = 0.0f;
        if (yy >= 0 && yy < HH && col >= 0 && col < WW)
            v = x[(((size_t)b * T_STEPS + u) * HH + yy) * WW + col];
        xs[dyi][xx] = v;
    }

    // Per-thread staging chunks: q0=tid, q1=256+tid (lds dst = base+tid*16).
    int q0 = tid, q1 = 256 + tid;
    int p0 = q0 >> 3, s0 = q0 & 7, cb0 = s0 ^ (p0 & 7);
    int p1 = q1 >> 3, s1 = q1 & 7, cb1 = s1 ^ (p1 & 7);

#define STAGE(KC, BUF)                                                        \
    {                                                                         \
        int tau_ = ((KC) < 9) ? (KC) : (KC) - 9;                              \
        const u16* src_ = ((KC) < 9) ? h0_prev : h1_prev;                     \
        int dy_ = tau_ / 3 - 1, dx_ = tau_ % 3 - 1;                           \
        const u16* rbase_ = src_ + (((size_t)(b * HP + y + dy_ + 1)) * HP +   \
                                    dx_ + 1) * FF;                            \
        gll16(rbase_ + (size_t)p0 * FF + cb0 * 8, &sA2[BUF][(size_t)q0 * 8]); \
        gll16(rbase_ + (size_t)p1 * FF + cb1 * 8, &sA2[BUF][(size_t)q1 * 8]); \
    }

    f32x4 acc[4][4];
#pragma unroll
    for (int mt = 0; mt < 4; ++mt)
#pragma unroll
        for (int g = 0; g < 4; ++g)
            acc[mt][g] = (f32x4){0.f, 0.f, 0.f, 0.f};

    STAGE(0, 0);
    __syncthreads();

    int sx = l15 & 7;
    for (int kc = 0; kc < nch; ++kc) {
        int cur = kc & 1;
        // B fragments for this chunk: coalesced stream reads, no LDS.
        const u16* bst = BS + (((size_t)kc << 14) | (fq << 12)) + (size_t)lane * 8;
        short8 bAll[8];
#pragma unroll
        for (int j = 0; j < 8; ++j)       // j = ks*4 + g
            bAll[j] = *(const short8*)(bst + ((size_t)j << 9));
        // Prefetch next A tile into the other buffer (async, in flight
        // until the barrier below).
        if (kc + 1 < nch) STAGE(kc + 1, cur ^ 1);
        // Compute on current A tile.
#pragma unroll
        for (int ks = 0; ks < 2; ++ks) {
            short8 aF[4];
#pragma unroll
            for (int mt = 0; mt < 4; ++mt) {
                int px = mt * 16 + l15;
                int chunk = px * 8 + ((ks * 4 + quad) ^ sx);
                aF[mt] = *(const short8*)&sA2[cur][(size_t)chunk * 8];
            }
#pragma unroll
            for (int mt = 0; mt < 4; ++mt)
#pragma unroll
                for (int g = 0; g < 4; ++g)
                    acc[mt][g] = __builtin_amdgcn_mfma_f32_16x16x32_bf16(
                        aF[mt], bAll[ks * 4 + g], acc[mt][g], 0, 0, 0);
        }
        __syncthreads();   // drains gll (vmcnt) + frees cur for kc+2
    }

    // ---- epilogue: LSTM gate update (lane-local: f = fq*16+l15) ----
    const float* bias = role ? b1 : b0;
    float* cbuf = role ? c1 : c0;
    u16* hout = role ? h1_new : h0_new;
    int wo = role ? (u == T_STEPS) : (u == T_STEPS - 1);
    float* outh = role ? oh1 : oh0;
    float* outc = role ? oc1 : oc0;

    int f = fq * 16 + l15;
    float bi = bias[f], bff = bias[64 + f], bg = bias[128 + f], bo = bias[192 + f];
    float wk[4][9];
    if (role == 0) {
#pragma unroll
        for (int g = 0; g < 4; ++g)
#pragma unroll
            for (int tau = 0; tau < 9; ++tau)
                wk[g][tau] = k0w[tau * NGATE + g * 64 + f];
    }
#pragma unroll
    for (int mt = 0; mt < 4; ++mt) {
#pragma unroll
        for (int r = 0; r < 4; ++r) {
            int xcol = mt * 16 + quad * 4 + r;      // pixel x within the row
            size_t p = (size_t)pxb * 64 + xcol;     // global pixel
            float zi = acc[mt][0][r] + bi;
            float zf = acc[mt][1][r] + bff;
            float zg = acc[mt][2][r] + bg;
            float zo = acc[mt][3][r] + bo;
            if (role == 0) {   // fused layer-0 input conv, fp32 exact
#pragma unroll
                for (int tau = 0; tau < 9; ++tau) {
                    float xv = xs[tau / 3][xcol + tau % 3];
                    zi += xv * wk[0][tau];
                    zf += xv * wk[1][tau];
                    zg += xv * wk[2][tau];
                    zo += xv * wk[3][tau];
                }
            }
            float cold = cbuf[p * FF + f];
            float cn = hsig(zf) * cold + hsig(zi) * ftanh(zg);
            float hn = hsig(zo) * ftanh(cn);
            cbuf[p * FF + f] = cn;
            hout[(((size_t)(b * HP + y + 1)) * HP + (xcol + 1)) * FF + f] = f2bf(hn);
            if (wo) { outh[p * FF + f] = hn; outc[p * FF + f] = cn; }
        }
    }
}

extern "C" void kernel_launch(void* const* d_in, const int* in_sizes, int n_in,
                              void* d_out, int out_size, void* d_ws, size_t ws_size,
                              hipStream_t stream) {
    const float* x   = (const float*)d_in[0];
    const float* k0  = (const float*)d_in[1];
    const float* rk0 = (const float*)d_in[2];
    const float* b0  = (const float*)d_in[3];
    const float* k1  = (const float*)d_in[4];
    const float* rk1 = (const float*)d_in[5];
    const float* b1  = (const float*)d_in[6];
    float* out = (float*)d_out;

    char* ws = (char*)d_ws;
    const size_t HPAD_BYTES = (size_t)NB * HP * HP * FF * 2;  // 4,460,544
    const size_t C_BYTES    = (size_t)PIX * FF * 4;           // 8,388,608

    u16* h0p[2]; u16* h1p[2];
    h0p[0] = (u16*)(ws);
    h0p[1] = (u16*)(ws + HPAD_BYTES);
    h1p[0] = (u16*)(ws + 2 * HPAD_BYTES);
    h1p[1] = (u16*)(ws + 3 * HPAD_BYTES);
    float* c0 = (float*)(ws + 4 * HPAD_BYTES);
    float* c1 = (float*)(ws + 4 * HPAD_BYTES + C_BYTES);
    u16* B0S  = (u16*)(ws + 4 * HPAD_BYTES + 2 * C_BYTES);
    u16* B1S  = (u16*)(ws + 4 * HPAD_BYTES + 2 * C_BYTES + (size_t)9 * 16384 * 2);

    // Zero h (incl. halo == SAME padding) and c states; ws is poisoned 0xAA.
    hipMemsetAsync(ws, 0, 4 * HPAD_BYTES + 2 * C_BYTES, stream);

    wtrans_kernel<<<512, 256, 0, stream>>>(rk0, rk0, B0S, 576);
    wtrans_kernel<<<512, 256, 0, stream>>>(k1, rk1, B1S, 1152);

    float* oh0 = out;
    float* oc0 = out + (size_t)PIX * FF;
    float* oh1 = out + 2 * (size_t)PIX * FF;
    float* oc1 = out + 3 * (size_t)PIX * FF;

    // Tick u: layer-0 computes step u (reads h0[u-1] -> writes h0[u]);
    //         layer-1 computes step u-1 (reads h0[u-1], h1[u-2] -> h1[u-1]).
    for (int u = 0; u <= T_STEPS; ++u) {
        const u16* h0_prev = h0p[(u + 1) & 1];
        u16*       h0_new  = h0p[u & 1];
        const u16* h1_prev = h1p[u & 1];
        u16*       h1_new  = h1p[(u + 1) & 1];
        fused_step_kernel<<<1024, 256, 0, stream>>>(
            h0_prev, h0_new, h1_prev, h1_new, B0S, B1S,
            x, k0, b0, b1, c0, c1, oh0, oc0, oh1, oc1, u);
    }
}

// Round 5
// 507.700 us; speedup vs baseline: 4.2752x; 1.0528x over previous
//
#include <hip/hip_runtime.h>
#include <hip/hip_bf16.h>

typedef unsigned short u16;
typedef __attribute__((ext_vector_type(8))) short short8;
typedef __attribute__((ext_vector_type(4))) float f32x4;

#define T_STEPS 10
#define NB 8
#define HH 64
#define WW 64
#define FF 64
#define NGATE 256
#define HP 66
#define PIX (NB*HH*WW)          // 32768

__device__ __forceinline__ u16 f2bf(float f) {
    unsigned u = __float_as_uint(f);
    u += 0x7FFF + ((u >> 16) & 1);   // round-to-nearest-even
    return (u16)(u >> 16);
}
__device__ __forceinline__ float hsig(float x) {
    return fminf(fmaxf(0.2f * x + 0.5f, 0.0f), 1.0f);
}
__device__ __forceinline__ float ftanh(float x) {
    float e = __expf(2.0f * x);
    return 1.0f - 2.0f / (e + 1.0f);
}
__device__ __forceinline__ void gll16(const void* g, void* l) {
    __builtin_amdgcn_global_load_lds(
        (const __attribute__((address_space(1))) unsigned*)g,
        (__attribute__((address_space(3))) unsigned*)l, 16, 0, 0);
}

// Build B in MFMA-fragment-stream order, bf16:
//   stream[kc][fq][ks][g][lane][e]; value = W[kc*64+ks*32+quad*8+e][g*64+fq*16+l15]
__global__ void wtrans_kernel(const float* __restrict__ W0,
                              const float* __restrict__ W1,
                              u16* __restrict__ BS, int K) {
    int total = (K >> 6) << 14;
    for (int o = blockIdx.x * blockDim.x + threadIdx.x; o < total;
         o += gridDim.x * blockDim.x) {
        int e = o & 7, lane = (o >> 3) & 63, g = (o >> 9) & 3;
        int ks = (o >> 11) & 1, fq = (o >> 12) & 3, kc = o >> 14;
        int quad = lane >> 4, l15 = lane & 15;
        int n = g * 64 + fq * 16 + l15;
        int k = kc * 64 + ks * 32 + quad * 8 + e;
        float v = (k < 576) ? W0[k * NGATE + n] : W1[(k - 576) * NGATE + n];
        BS[o] = f2bf(v);
    }
}

__device__ __forceinline__ void stageA(const u16* __restrict__ h0_prev,
                                       const u16* __restrict__ h1_prev,
                                       int kcs, int b, int y,
                                       int p0, int cb0, int p1, int cb1,
                                       u16* ldst0, u16* ldst1) {
    int tau = (kcs < 9) ? kcs : kcs - 9;
    const u16* src = (kcs < 9) ? h0_prev : h1_prev;
    int dy = tau / 3 - 1, dx = tau % 3 - 1;
    const u16* rbase = src + (((size_t)(b * HP + y + dy + 1)) * HP + dx + 1) * FF;
    gll16(rbase + (size_t)p0 * FF + cb0 * 8, ldst0);
    gll16(rbase + (size_t)p1 * FF + cb1 * 8, ldst1);
}

// Fused dual-layer ConvLSTM tick; XCD-local batches (batch = blockIdx & 7).
// A: triple-buffered LDS via global_load_lds, distance-2 prefetch kept in
// flight ACROSS barriers (raw s_barrier + vmcnt(2): the 2 newest VM ops are
// the glls for chunk kc+2 — every B load has an MFMA use before them, so
// vmcnt(2) drains gll(kc+1) + all B loads, keeps gll(kc+2) in flight).
// B: direct from global fragment stream (XCD-L2-resident), no LDS.
__global__ __launch_bounds__(256, 4)
void fused_step_kernel(const u16* __restrict__ h0_prev, u16* __restrict__ h0_new,
                       const u16* __restrict__ h1_prev, u16* __restrict__ h1_new,
                       const u16* __restrict__ B0S, const u16* __restrict__ B1S,
                       const float* __restrict__ x, const float* __restrict__ k0w,
                       const float* __restrict__ b0, const float* __restrict__ b1,
                       float* __restrict__ c0, float* __restrict__ c1,
                       float* __restrict__ oh0, float* __restrict__ oc0,
                       float* __restrict__ oh1, float* __restrict__ oc1,
                       int u) {
    int blk = blockIdx.x;
    int b = blk & 7;                 // batch == XCD (blockIdx % 8 round-robin)
    int role = (blk >> 3) & 1;       // 0: layer-0 step u; 1: layer-1 step u-1
    int y = blk >> 4;                // image row
    int pxb = b * 64 + y;
    if (role == 0 && u >= T_STEPS) return;
    if (role == 1 && u == 0) return;

    // A tile: 512 16B-chunks; chunk q holds px=q>>3, ch-block (q&7)^(px&7).
    __shared__ __align__(16) u16 sA3[3][4096];
    __shared__ float xs[3][WW + 2];

    int tid = threadIdx.x;
    int lane = tid & 63, fq = tid >> 6;
    int quad = lane >> 4, l15 = lane & 15;

    const u16* BS = role ? B1S : B0S;
    int nch = role ? 18 : 9;

    if (role == 0 && tid < 3 * (WW + 2)) {
        int dyi = tid / (WW + 2), xx = tid - dyi * (WW + 2);
        int yy = y + dyi - 1, col = xx - 1;
        float v = 0.0f;
        if (yy >= 0 && yy < HH && col >= 0 && col < WW)
            v = x[(((size_t)b * T_STEPS + u) * HH + yy) * WW + col];
        xs[dyi][xx] = v;
    }

    // Per-thread staging chunks: q0=tid, q1=256+tid (lds dst = base+tid*16,
    // wave-uniform base + lane*16 as global_load_lds requires).
    int q0 = tid, q1 = 256 + tid;
    int p0 = q0 >> 3, cb0 = (q0 & 7) ^ (p0 & 7);
    int p1 = q1 >> 3, cb1 = (q1 & 7) ^ (p1 & 7);

    f32x4 acc[4][4];
#pragma unroll
    for (int mt = 0; mt < 4; ++mt)
#pragma unroll
        for (int g = 0; g < 4; ++g)
            acc[mt][g] = (f32x4){0.f, 0.f, 0.f, 0.f};

    // ---- pipeline prologue ----
    stageA(h0_prev, h1_prev, 0, b, y, p0, cb0, p1, cb1,
           &sA3[0][(size_t)q0 * 8], &sA3[0][(size_t)q1 * 8]);
    asm volatile("s_waitcnt vmcnt(0) lgkmcnt(0)\n\ts_barrier" ::: "memory");
    if (nch > 1)
        stageA(h0_prev, h1_prev, 1, b, y, p0, cb0, p1, cb1,
               &sA3[1][(size_t)q0 * 8], &sA3[1][(size_t)q1 * 8]);

    int sx = l15 & 7;
    int cur = 0;
    for (int kc = 0; kc < nch; ++kc) {
        // compute on buffer cur (gll(kc) drained by previous barrier)
#pragma unroll
        for (int ks = 0; ks < 2; ++ks) {
            short8 bF[4];
            const u16* bp = BS + (((size_t)kc << 14) | (fq << 12) | (ks << 11))
                          + lane * 8;
#pragma unroll
            for (int g = 0; g < 4; ++g)
                bF[g] = *(const short8*)(bp + ((size_t)g << 9));
            short8 aF[4];
#pragma unroll
            for (int mt = 0; mt < 4; ++mt) {
                int px = mt * 16 + l15;
                int chunk = px * 8 + ((ks * 4 + quad) ^ sx);
                aF[mt] = *(const short8*)&sA3[cur][(size_t)chunk * 8];
            }
#pragma unroll
            for (int mt = 0; mt < 4; ++mt)
#pragma unroll
                for (int g = 0; g < 4; ++g)
                    acc[mt][g] = __builtin_amdgcn_mfma_f32_16x16x32_bf16(
                        aF[mt], bF[g], acc[mt][g], 0, 0, 0);
        }
        // distance-2 prefetch; dummy re-stage of an unread buffer in the tail
        // keeps the per-iteration vmcnt count uniform (always 2 glls issued).
        {
            int ksrc = (kc + 2 < nch) ? kc + 2 : kc;
            int bdst = (cur + 2 >= 3) ? cur - 1 : cur + 2;
            stageA(h0_prev, h1_prev, ksrc, b, y, p0, cb0, p1, cb1,
                   &sA3[bdst][(size_t)q0 * 8], &sA3[bdst][(size_t)q1 * 8]);
        }
        // drain gll(kc+1) (+ all B loads); keep gll(kc+2) in flight.
        asm volatile("s_waitcnt vmcnt(2) lgkmcnt(0)\n\ts_barrier" ::: "memory");
        cur = (cur == 2) ? 0 : cur + 1;
    }

    // ---- epilogue: LSTM gate update (lane-local: f = fq*16+l15) ----
    const float* bias = role ? b1 : b0;
    float* cbuf = role ? c1 : c0;
    u16* hout = role ? h1_new : h0_new;
    int wo = role ? (u == T_STEPS) : (u == T_STEPS - 1);
    float* outh = role ? oh1 : oh0;
    float* outc = role ? oc1 : oc0;

    int f = fq * 16 + l15;
    float bi = bias[f], bff = bias[64 + f], bg = bias[128 + f], bo = bias[192 + f];
    float wk[4][9];
    if (role == 0) {
#pragma unroll
        for (int g = 0; g < 4; ++g)
#pragma unroll
            for (int tau = 0; tau < 9; ++tau)
                wk[g][tau] = k0w[tau * NGATE + g * 64 + f];
    }
#pragma unroll
    for (int mt = 0; mt < 4; ++mt) {
#pragma unroll
        for (int r = 0; r < 4; ++r) {
            int xcol = mt * 16 + quad * 4 + r;      // pixel x within the row
            size_t p = (size_t)pxb * 64 + xcol;     // global pixel
            float zi = acc[mt][0][r] + bi;
            float zf = acc[mt][1][r] + bff;
            float zg = acc[mt][2][r] + bg;
            float zo = acc[mt][3][r] + bo;
            if (role == 0) {   // fused layer-0 input conv, fp32 exact
#pragma unroll
                for (int tau = 0; tau < 9; ++tau) {
                    float xv = xs[tau / 3][xcol + tau % 3];
                    zi += xv * wk[0][tau];
                    zf += xv * wk[1][tau];
                    zg += xv * wk[2][tau];
                    zo += xv * wk[3][tau];
                }
            }
            float cold = cbuf[p * FF + f];
            float cn = hsig(zf) * cold + hsig(zi) * ftanh(zg);
            float hn = hsig(zo) * ftanh(cn);
            cbuf[p * FF + f] = cn;
            hout[(((size_t)(b * HP + y + 1)) * HP + (xcol + 1)) * FF + f] = f2bf(hn);
            if (wo) { outh[p * FF + f] = hn; outc[p * FF + f] = cn; }
        }
    }
}

extern "C" void kernel_launch(void* const* d_in, const int* in_sizes, int n_in,
                              void* d_out, int out_size, void* d_ws, size_t ws_size,
                              hipStream_t stream) {
    const float* x   = (const float*)d_in[0];
    const float* k0  = (const float*)d_in[1];
    const float* rk0 = (const float*)d_in[2];
    const float* b0  = (const float*)d_in[3];
    const float* k1  = (const float*)d_in[4];
    const float* rk1 = (const float*)d_in[5];
    const float* b1  = (const float*)d_in[6];
    float* out = (float*)d_out;

    char* ws = (char*)d_ws;
    const size_t HPAD_BYTES = (size_t)NB * HP * HP * FF * 2;  // 4,460,544
    const size_t C_BYTES    = (size_t)PIX * FF * 4;           // 8,388,608

    u16* h0p[2]; u16* h1p[2];
    h0p[0] = (u16*)(ws);
    h0p[1] = (u16*)(ws + HPAD_BYTES);
    h1p[0] = (u16*)(ws + 2 * HPAD_BYTES);
    h1p[1] = (u16*)(ws + 3 * HPAD_BYTES);
    float* c0 = (float*)(ws + 4 * HPAD_BYTES);
    float* c1 = (float*)(ws + 4 * HPAD_BYTES + C_BYTES);
    u16* B0S  = (u16*)(ws + 4 * HPAD_BYTES + 2 * C_BYTES);
    u16* B1S  = (u16*)(ws + 4 * HPAD_BYTES + 2 * C_BYTES + (size_t)9 * 16384 * 2);

    // Zero h (incl. halo == SAME padding) and c states; ws is poisoned 0xAA.
    hipMemsetAsync(ws, 0, 4 * HPAD_BYTES + 2 * C_BYTES, stream);

    wtrans_kernel<<<512, 256, 0, stream>>>(rk0, rk0, B0S, 576);
    wtrans_kernel<<<512, 256, 0, stream>>>(k1, rk1, B1S, 1152);

    float* oh0 = out;
    float* oc0 = out + (size_t)PIX * FF;
    float* oh1 = out + 2 * (size_t)PIX * FF;
    float* oc1 = out + 3 * (size_t)PIX * FF;

    // Tick u: layer-0 computes step u (reads h0[u-1] -> writes h0[u]);
    //         layer-1 computes step u-1 (reads h0[u-1], h1[u-2] -> h1[u-1]).
    for (int u = 0; u <= T_STEPS; ++u) {
        const u16* h0_prev = h0p[(u + 1) & 1];
        u16*       h0_new  = h0p[u & 1];
        const u16* h1_prev = h1p[u & 1];
        u16*       h1_new  = h1p[(u + 1) & 1];
        fused_step_kernel<<<1024, 256, 0, stream>>>(
            h0_prev, h0_new, h1_prev, h1_new, B0S, B1S,
            x, k0, b0, b1, c0, c1, oh0, oc0, oh1, oc1, u);
    }
}

// Round 6
// 483.459 us; speedup vs baseline: 4.4895x; 1.0501x over previous
//
#include <hip/hip_runtime.h>
#include <hip/hip_bf16.h>

typedef unsigned short u16;
typedef __attribute__((ext_vector_type(8))) short short8;
typedef __attribute__((ext_vector_type(4))) float f32x4;

#define T_STEPS 10
#define NB 8
#define HH 64
#define WW 64
#define FF 64
#define NGATE 256
#define HP 66
#define PIX (NB*HH*WW)          // 32768

__device__ __forceinline__ u16 f2bf(float f) {
    unsigned u = __float_as_uint(f);
    u += 0x7FFF + ((u >> 16) & 1);   // round-to-nearest-even
    return (u16)(u >> 16);
}
__device__ __forceinline__ float hsig(float x) {
    return fminf(fmaxf(0.2f * x + 0.5f, 0.0f), 1.0f);
}
__device__ __forceinline__ float ftanh(float x) {
    float e = __expf(2.0f * x);
    return 1.0f - 2.0f / (e + 1.0f);
}
__device__ __forceinline__ void gll16(const void* g, void* l) {
    __builtin_amdgcn_global_load_lds(
        (const __attribute__((address_space(1))) unsigned*)g,
        (__attribute__((address_space(3))) unsigned*)l, 16, 0, 0);
}

// Build B in MFMA-fragment-stream order, bf16:
//   stream[kc][fq][ks][g][lane][e]; value = W[kc*64+ks*32+quad*8+e][g*64+fq*16+l15]
__global__ void wtrans_kernel(const float* __restrict__ W0,
                              const float* __restrict__ W1,
                              u16* __restrict__ BS, int K) {
    int total = (K >> 6) << 14;
    for (int o = blockIdx.x * blockDim.x + threadIdx.x; o < total;
         o += gridDim.x * blockDim.x) {
        int e = o & 7, lane = (o >> 3) & 63, g = (o >> 9) & 3;
        int ks = (o >> 11) & 1, fq = (o >> 12) & 3, kc = o >> 14;
        int quad = lane >> 4, l15 = lane & 15;
        int n = g * 64 + fq * 16 + l15;
        int k = kc * 64 + ks * 32 + quad * 8 + e;
        float v = (k < 576) ? W0[k * NGATE + n] : W1[(k - 576) * NGATE + n];
        BS[o] = f2bf(v);
    }
}

__device__ __forceinline__ void stageA(const u16* __restrict__ h0_prev,
                                       const u16* __restrict__ h1_prev,
                                       int kcs, int b, int y,
                                       int p0, int cb0, int p1, int cb1,
                                       u16* ldst0, u16* ldst1) {
    int tau = (kcs < 9) ? kcs : kcs - 9;
    const u16* src = (kcs < 9) ? h0_prev : h1_prev;
    int dy = tau / 3 - 1, dx = tau % 3 - 1;
    const u16* rbase = src + (((size_t)(b * HP + y + dy + 1)) * HP + dx + 1) * FF;
    gll16(rbase + (size_t)p0 * FF + cb0 * 8, ldst0);
    gll16(rbase + (size_t)p1 * FF + cb1 * 8, ldst1);
}

// Fused dual-layer ConvLSTM tick; XCD-local batches (batch = blockIdx & 7).
// Block decode balances ROLES PER CU: with round-robin dispatch (XCD-local
// index k -> CU k%32), role=(k>>5)&1 gives every CU 2 role-0 + 2 role-1
// blocks (54 chunks/CU uniform) instead of 4x9 vs 4x18 (2x imbalance).
// A: triple-buffered LDS via global_load_lds, distance-2 prefetch kept in
// flight ACROSS barriers (raw s_barrier + vmcnt(2)).
// B: direct from global fragment stream (XCD-L2-resident), no LDS.
__global__ __launch_bounds__(256, 4)
void fused_step_kernel(const u16* __restrict__ h0_prev, u16* __restrict__ h0_new,
                       const u16* __restrict__ h1_prev, u16* __restrict__ h1_new,
                       const u16* __restrict__ B0S, const u16* __restrict__ B1S,
                       const float* __restrict__ x, const float* __restrict__ k0w,
                       const float* __restrict__ b0, const float* __restrict__ b1,
                       float* __restrict__ c0, float* __restrict__ c1,
                       float* __restrict__ oh0, float* __restrict__ oc0,
                       float* __restrict__ oh1, float* __restrict__ oc1,
                       int u) {
    int blk = blockIdx.x;
    int b = blk & 7;                 // batch == XCD (blockIdx % 8 round-robin)
    int k = blk >> 3;                // XCD-local index 0..127 (-> CU k%32)
    int role = (k >> 5) & 1;         // 0: layer-0 step u; 1: layer-1 step u-1
    int y = (k & 31) | ((k >> 6) << 5);   // image row 0..63
    int pxb = b * 64 + y;
    if (role == 0 && u >= T_STEPS) return;
    if (role == 1 && u == 0) return;

    // A tile: 512 16B-chunks; chunk q holds px=q>>3, ch-block (q&7)^(px&7).
    __shared__ __align__(16) u16 sA3[3][4096];
    __shared__ float xs[3][WW + 2];

    int tid = threadIdx.x;
    int lane = tid & 63, fq = tid >> 6;
    int quad = lane >> 4, l15 = lane & 15;

    const u16* BS = role ? B1S : B0S;
    int nch = role ? 18 : 9;

    if (role == 0 && tid < 3 * (WW + 2)) {
        int dyi = tid / (WW + 2), xx = tid - dyi * (WW + 2);
        int yy = y + dyi - 1, col = xx - 1;
        float v = 0.0f;
        if (yy >= 0 && yy < HH && col >= 0 && col < WW)
            v = x[(((size_t)b * T_STEPS + u) * HH + yy) * WW + col];
        xs[dyi][xx] = v;
    }

    // Per-thread staging chunks: q0=tid, q1=256+tid (lds dst = base+tid*16,
    // wave-uniform base + lane*16 as global_load_lds requires).
    int q0 = tid, q1 = 256 + tid;
    int p0 = q0 >> 3, cb0 = (q0 & 7) ^ (p0 & 7);
    int p1 = q1 >> 3, cb1 = (q1 & 7) ^ (p1 & 7);

    f32x4 acc[4][4];
#pragma unroll
    for (int mt = 0; mt < 4; ++mt)
#pragma unroll
        for (int g = 0; g < 4; ++g)
            acc[mt][g] = (f32x4){0.f, 0.f, 0.f, 0.f};

    // ---- pipeline prologue ----
    stageA(h0_prev, h1_prev, 0, b, y, p0, cb0, p1, cb1,
           &sA3[0][(size_t)q0 * 8], &sA3[0][(size_t)q1 * 8]);
    asm volatile("s_waitcnt vmcnt(0) lgkmcnt(0)\n\ts_barrier" ::: "memory");
    if (nch > 1)
        stageA(h0_prev, h1_prev, 1, b, y, p0, cb0, p1, cb1,
               &sA3[1][(size_t)q0 * 8], &sA3[1][(size_t)q1 * 8]);

    int sx = l15 & 7;
    int cur = 0;
    for (int kc = 0; kc < nch; ++kc) {
        // compute on buffer cur (gll(kc) drained by previous barrier)
#pragma unroll
        for (int ks = 0; ks < 2; ++ks) {
            short8 bF[4];
            const u16* bp = BS + (((size_t)kc << 14) | (fq << 12) | (ks << 11))
                          + lane * 8;
#pragma unroll
            for (int g = 0; g < 4; ++g)
                bF[g] = *(const short8*)(bp + ((size_t)g << 9));
            short8 aF[4];
#pragma unroll
            for (int mt = 0; mt < 4; ++mt) {
                int px = mt * 16 + l15;
                int chunk = px * 8 + ((ks * 4 + quad) ^ sx);
                aF[mt] = *(const short8*)&sA3[cur][(size_t)chunk * 8];
            }
#pragma unroll
            for (int mt = 0; mt < 4; ++mt)
#pragma unroll
                for (int g = 0; g < 4; ++g)
                    acc[mt][g] = __builtin_amdgcn_mfma_f32_16x16x32_bf16(
                        aF[mt], bF[g], acc[mt][g], 0, 0, 0);
        }
        // distance-2 prefetch; dummy re-stage of an unread buffer in the tail
        // keeps the per-iteration vmcnt count uniform (always 2 glls issued).
        {
            int ksrc = (kc + 2 < nch) ? kc + 2 : kc;
            int bdst = (cur + 2 >= 3) ? cur - 1 : cur + 2;
            stageA(h0_prev, h1_prev, ksrc, b, y, p0, cb0, p1, cb1,
                   &sA3[bdst][(size_t)q0 * 8], &sA3[bdst][(size_t)q1 * 8]);
        }
        // drain gll(kc+1) (+ all B loads); keep gll(kc+2) in flight.
        asm volatile("s_waitcnt vmcnt(2) lgkmcnt(0)\n\ts_barrier" ::: "memory");
        cur = (cur == 2) ? 0 : cur + 1;
    }

    // ---- epilogue: LSTM gate update (lane-local: f = fq*16+l15) ----
    const float* bias = role ? b1 : b0;
    float* cbuf = role ? c1 : c0;
    u16* hout = role ? h1_new : h0_new;
    int wo = role ? (u == T_STEPS) : (u == T_STEPS - 1);
    float* outh = role ? oh1 : oh0;
    float* outc = role ? oc1 : oc0;

    int f = fq * 16 + l15;
    float bi = bias[f], bff = bias[64 + f], bg = bias[128 + f], bo = bias[192 + f];
    float wk[4][9];
    if (role == 0) {
#pragma unroll
        for (int g = 0; g < 4; ++g)
#pragma unroll
            for (int tau = 0; tau < 9; ++tau)
                wk[g][tau] = k0w[tau * NGATE + g * 64 + f];
    }
#pragma unroll
    for (int mt = 0; mt < 4; ++mt) {
#pragma unroll
        for (int r = 0; r < 4; ++r) {
            int xcol = mt * 16 + quad * 4 + r;      // pixel x within the row
            size_t p = (size_t)pxb * 64 + xcol;     // global pixel
            float zi = acc[mt][0][r] + bi;
            float zf = acc[mt][1][r] + bff;
            float zg = acc[mt][2][r] + bg;
            float zo = acc[mt][3][r] + bo;
            if (role == 0) {   // fused layer-0 input conv, fp32 exact
#pragma unroll
                for (int tau = 0; tau < 9; ++tau) {
                    float xv = xs[tau / 3][xcol + tau % 3];
                    zi += xv * wk[0][tau];
                    zf += xv * wk[1][tau];
                    zg += xv * wk[2][tau];
                    zo += xv * wk[3][tau];
                }
            }
            float cold = cbuf[p * FF + f];
            float cn = hsig(zf) * cold + hsig(zi) * ftanh(zg);
            float hn = hsig(zo) * ftanh(cn);
            cbuf[p * FF + f] = cn;
            hout[(((size_t)(b * HP + y + 1)) * HP + (xcol + 1)) * FF + f] = f2bf(hn);
            if (wo) { outh[p * FF + f] = hn; outc[p * FF + f] = cn; }
        }
    }
}

extern "C" void kernel_launch(void* const* d_in, const int* in_sizes, int n_in,
                              void* d_out, int out_size, void* d_ws, size_t ws_size,
                              hipStream_t stream) {
    const float* x   = (const float*)d_in[0];
    const float* k0  = (const float*)d_in[1];
    const float* rk0 = (const float*)d_in[2];
    const float* b0  = (const float*)d_in[3];
    const float* k1  = (const float*)d_in[4];
    const float* rk1 = (const float*)d_in[5];
    const float* b1  = (const float*)d_in[6];
    float* out = (float*)d_out;

    char* ws = (char*)d_ws;
    const size_t HPAD_BYTES = (size_t)NB * HP * HP * FF * 2;  // 4,460,544
    const size_t C_BYTES    = (size_t)PIX * FF * 4;           // 8,388,608

    u16* h0p[2]; u16* h1p[2];
    h0p[0] = (u16*)(ws);
    h0p[1] = (u16*)(ws + HPAD_BYTES);
    h1p[0] = (u16*)(ws + 2 * HPAD_BYTES);
    h1p[1] = (u16*)(ws + 3 * HPAD_BYTES);
    float* c0 = (float*)(ws + 4 * HPAD_BYTES);
    float* c1 = (float*)(ws + 4 * HPAD_BYTES + C_BYTES);
    u16* B0S  = (u16*)(ws + 4 * HPAD_BYTES + 2 * C_BYTES);
    u16* B1S  = (u16*)(ws + 4 * HPAD_BYTES + 2 * C_BYTES + (size_t)9 * 16384 * 2);

    // Zero h (incl. halo == SAME padding) and c states; ws is poisoned 0xAA.
    hipMemsetAsync(ws, 0, 4 * HPAD_BYTES + 2 * C_BYTES, stream);

    wtrans_kernel<<<512, 256, 0, stream>>>(rk0, rk0, B0S, 576);
    wtrans_kernel<<<512, 256, 0, stream>>>(k1, rk1, B1S, 1152);

    float* oh0 = out;
    float* oc0 = out + (size_t)PIX * FF;
    float* oh1 = out + 2 * (size_t)PIX * FF;
    float* oc1 = out + 3 * (size_t)PIX * FF;

    // Tick u: layer-0 computes step u (reads h0[u-1] -> writes h0[u]);
    //         layer-1 computes step u-1 (reads h0[u-1], h1[u-2] -> h1[u-1]).
    for (int u = 0; u <= T_STEPS; ++u) {
        const u16* h0_prev = h0p[(u + 1) & 1];
        u16*       h0_new  = h0p[u & 1];
        const u16* h1_prev = h1p[u & 1];
        u16*       h1_new  = h1p[(u + 1) & 1];
        fused_step_kernel<<<1024, 256, 0, stream>>>(
            h0_prev, h0_new, h1_prev, h1_new, B0S, B1S,
            x, k0, b0, b1, c0, c1, oh0, oc0, oh1, oc1, u);
    }
}